// Round 13
// baseline (1017.221 us; speedup 1.0000x reference)
//
#include <hip/hip_runtime.h>
#include <stdint.h>
#include <math.h>

// ---------------- problem constants ----------------
#define LSEQ   1024
#define DMODEL 512
#define NH     8
#define DH     64
#define DFF    2048
#define NB     8
#define NLAYER 3
#define UTOP   35
#define NCLS   16
#define WPERL  3145728   // fp16 weight elements per layer: [Wq|Wk|Wv|Wo|W1|W2]

typedef unsigned short u16;
typedef _Float16 f16x8 __attribute__((ext_vector_type(8)));
typedef __attribute__((ext_vector_type(4))) float f32x4;

// fp16 helpers (RNE)
__device__ __forceinline__ u16 f2h(float f) {
  _Float16 h = (_Float16)f;
  return __builtin_bit_cast(u16, h);
}
__device__ __forceinline__ float h2f(u16 b) {
  return (float)__builtin_bit_cast(_Float16, b);
}

#define GLDS16(gsrc, ldst)                                                        \
  __builtin_amdgcn_global_load_lds(                                              \
      (const __attribute__((address_space(1))) void*)(gsrc),                     \
      (__attribute__((address_space(3))) void*)(ldst), 16, 0, 0)

// ---------------- threefry2x32 (exact JAX semantics) ----------------
__host__ __device__ __forceinline__ uint32_t rotl32(uint32_t x, int d) {
  return (x << d) | (x >> (32 - d));
}
__host__ __device__ inline void tf2x32(uint32_t k0, uint32_t k1,
                                       uint32_t c0, uint32_t c1,
                                       uint32_t& o0, uint32_t& o1) {
  uint32_t ks2 = k0 ^ k1 ^ 0x1BD11BDAu;
  uint32_t x0 = c0 + k0, x1 = c1 + k1;
#define TF_R4(a,b,c,d) \
  x0 += x1; x1 = rotl32(x1,(a)); x1 ^= x0; \
  x0 += x1; x1 = rotl32(x1,(b)); x1 ^= x0; \
  x0 += x1; x1 = rotl32(x1,(c)); x1 ^= x0; \
  x0 += x1; x1 = rotl32(x1,(d)); x1 ^= x0;
  TF_R4(13,15,26,6)   x0 += k1;  x1 += ks2 + 1u;
  TF_R4(17,29,16,24)  x0 += ks2; x1 += k0 + 2u;
  TF_R4(13,15,26,6)   x0 += k0;  x1 += k1 + 3u;
  TF_R4(17,29,16,24)  x0 += k1;  x1 += ks2 + 4u;
  TF_R4(13,15,26,6)   x0 += ks2; x1 += k0 + 5u;
#undef TF_R4
  o0 = x0; o1 = x1;
}

__global__ void __launch_bounds__(256) gen_idx_kernel(uint32_t k0, uint32_t k1,
                                                      int* idx) {
  int i = blockIdx.x * 256 + threadIdx.x;
  if (i >= LSEQ * UTOP) return;
  uint32_t a, b;
  tf2x32(k0, k1, 0u, (uint32_t)i, a, b);
  idx[i] = (int)((a ^ b) & (LSEQ - 1));
}

// ---------------- ALL weights fp32 -> fp16, one dispatch ----------------
__global__ void __launch_bounds__(256) cvt_all(
    const float* __restrict__ Wq, const float* __restrict__ Wk,
    const float* __restrict__ Wv, const float* __restrict__ Wo,
    const float* __restrict__ W1, const float* __restrict__ W2,
    u16* __restrict__ dst) {
  const size_t total = (size_t)NLAYER * WPERL;
  for (size_t i4 = ((size_t)blockIdx.x * 256 + threadIdx.x) * 4;
       i4 < total; i4 += (size_t)gridDim.x * 256 * 4) {
    int l = (int)(i4 / WPERL);
    int off = (int)(i4 % WPERL);
    const float* src; size_t so;
    if (off < 262144)       { src = Wq; so = (size_t)l * 262144  + off; }
    else if (off < 524288)  { src = Wk; so = (size_t)l * 262144  + off - 262144; }
    else if (off < 786432)  { src = Wv; so = (size_t)l * 262144  + off - 524288; }
    else if (off < 1048576) { src = Wo; so = (size_t)l * 262144  + off - 786432; }
    else if (off < 2097152) { src = W1; so = (size_t)l * 1048576 + off - 1048576; }
    else                    { src = W2; so = (size_t)l * 1048576 + off - 2097152; }
    float4 v = *(const float4*)&src[so];
    ushort4 h;
    h.x = f2h(v.x); h.y = f2h(v.y); h.z = f2h(v.z); h.w = f2h(v.w);
    *(ushort4*)&dst[i4] = h;
  }
}

// ---------------- conv1d (circular pad 1) + PE, batch-parallel ----------------
__global__ void __launch_bounds__(256) conv_pe(const float* __restrict__ xe,
                                               const float* __restrict__ w,
                                               float* __restrict__ xout,
                                               u16* __restrict__ xh) {
  const int d0 = blockIdx.x * 64;
  const int l0 = blockIdx.y * 32;
  const int b  = blockIdx.z;
  const int tid = threadIdx.x;
  const int dl = tid & 63;
  const int lq = tid >> 6;
  __shared__ float ws_[64][97];
  __shared__ float xs[32][37];

  for (int i = tid; i < 64 * 96; i += 256) {
    int dd = i / 96, cc = i - dd * 96;
    ws_[dd][cc] = w[(size_t)(d0 + dd) * 96 + cc];
  }
  for (int i = tid; i < 34 * 32; i += 256) {
    int r = i >> 5, c = i & 31;
    int row = (l0 - 1 + r + LSEQ) & (LSEQ - 1);
    xs[c][r] = xe[((size_t)b * LSEQ + row) * 32 + c];
  }

  const int d = d0 + dl;
  float div = expf((float)(d & ~1) * (-9.210340371976184f / 512.0f));
  float pe[8];
  #pragma unroll
  for (int j = 0; j < 8; ++j) {
    float arg = (float)(l0 + lq * 8 + j) * div;
    pe[j] = (d & 1) ? cosf(arg) : sinf(arg);
  }
  __syncthreads();

  float acc[8] = {};
  #pragma unroll 4
  for (int c = 0; c < 32; ++c) {
    float w0 = ws_[dl][c * 3 + 0];
    float w1 = ws_[dl][c * 3 + 1];
    float w2 = ws_[dl][c * 3 + 2];
    float xv[10];
    #pragma unroll
    for (int r = 0; r < 10; ++r) xv[r] = xs[c][lq * 8 + r];
    #pragma unroll
    for (int j = 0; j < 8; ++j)
      acc[j] += xv[j] * w0 + xv[j + 1] * w1 + xv[j + 2] * w2;
  }
  #pragma unroll
  for (int j = 0; j < 8; ++j) {
    int l = l0 + lq * 8 + j;
    float v = acc[j] + pe[j];
    size_t m = (size_t)b * LSEQ + l;
    xout[m * DMODEL + d] = v;
    xh[m * DMODEL + d] = f2h(v);
  }
}

// ---------------- 256x256-tile plain-fp16 GEMM (8 waves, counted vmcnt) ------
__global__ void __launch_bounds__(512, 2) gemm256(
    const u16* __restrict__ A, const u16* __restrict__ W,
    const float* __restrict__ bias, const float* __restrict__ bias_k,
    const float* __restrict__ bias_v,
    float* __restrict__ Cf, u16* __restrict__ C2,
    int Kseg, int N, int mode) {
  __shared__ u16 As[2][256 * 64];
  __shared__ u16 Bs[2][256 * 64];
  const int tid = threadIdx.x;
  const int lane = tid & 63, wv = tid >> 6;     // 8 waves
  const int wm = wv >> 2, wn = wv & 3;          // 2 x 4
  const int pid = blockIdx.y * gridDim.x + blockIdx.x;
  const int cpx = (gridDim.x * gridDim.y) >> 3;
  const int swz = (pid & 7) * cpx + (pid >> 3);
  const int m0 = (swz / gridDim.x) * 256, n0 = (swz % gridDim.x) * 256;
  const int lrow = lane >> 3;
  const int kgS = (lane & 7) ^ lrow;
  const int nt = Kseg >> 6;

  f32x4 acc[8][4];
  #pragma unroll
  for (int i = 0; i < 8; ++i)
    #pragma unroll
    for (int j = 0; j < 4; ++j) acc[i][j] = (f32x4){0.f, 0.f, 0.f, 0.f};

  auto STAGE = [&](int kv, int buf) {
    #pragma unroll
    for (int r = 0; r < 4; ++r) {
      int seg = wv * 4 + r;
      int row = seg * 8 + lrow;
      GLDS16(A + (size_t)(m0 + row) * Kseg + kv + kgS * 8, &As[buf][seg * 512]);
      GLDS16(W + (size_t)(n0 + row) * Kseg + kv + kgS * 8, &Bs[buf][seg * 512]);
    }
  };

  STAGE(0, 0);
  for (int t = 0; t < nt; ++t) {
    const int cur = t & 1;
    if (t + 1 < nt) {
      STAGE((t + 1) * 64, cur ^ 1);
      asm volatile("s_waitcnt vmcnt(8)" ::: "memory");
    } else {
      asm volatile("s_waitcnt vmcnt(0)" ::: "memory");
    }
    __builtin_amdgcn_s_barrier();
    __builtin_amdgcn_sched_barrier(0);
    #pragma unroll
    for (int kk = 0; kk < 2; ++kk) {
      int kg = kk * 4 + (lane >> 4);
      f16x8 af[8], bf[4];
      #pragma unroll
      for (int mi = 0; mi < 8; ++mi) {
        int row = wm * 128 + mi * 16 + (lane & 15);
        af[mi] = *(const f16x8*)&As[cur][row * 64 + ((kg ^ (row & 7)) << 3)];
      }
      #pragma unroll
      for (int ni = 0; ni < 4; ++ni) {
        int row = wn * 64 + ni * 16 + (lane & 15);
        bf[ni] = *(const f16x8*)&Bs[cur][row * 64 + ((kg ^ (row & 7)) << 3)];
      }
      #pragma unroll
      for (int mi = 0; mi < 8; ++mi)
        #pragma unroll
        for (int ni = 0; ni < 4; ++ni)
          acc[mi][ni] = __builtin_amdgcn_mfma_f32_16x16x32_f16(
              af[mi], bf[ni], acc[mi][ni], 0, 0, 0);
    }
    __builtin_amdgcn_s_barrier();
  }

  const int colb = n0 + wn * 64 + (lane & 15);
  const int rowb = m0 + wm * 128 + ((lane >> 4) << 2);
  #pragma unroll
  for (int mi = 0; mi < 8; ++mi) {
    #pragma unroll
    for (int ni = 0; ni < 4; ++ni) {
      int gcol = colb + ni * 16;
      float bv;
      if (mode == 3) {
        int mat = gcol >> 9, c = gcol & 511;
        bv = (mat == 0 ? bias : (mat == 1 ? bias_k : bias_v))[c];
      } else {
        bv = bias[gcol];
      }
      #pragma unroll
      for (int j = 0; j < 4; ++j) {
        int grow = rowb + mi * 16 + j;
        float v = acc[mi][ni][j] + bv;
        if (mode == 1) {
          C2[(size_t)grow * N + gcol] = f2h(fmaxf(v, 0.f));
        } else {  // 3: fused QKV scatter
          int mat = gcol >> 9, c = gcol & 511;
          Cf[(size_t)mat * (NB * LSEQ * DMODEL) +
             (size_t)(grow >> 10) * (NH * LSEQ * DH) +
             (size_t)(c >> 6) * (LSEQ * DH) +
             (size_t)(grow & (LSEQ - 1)) * DH + (c & (DH - 1))] = v;
        }
      }
    }
  }
}

// ---------------- 128-tile plain-fp16 GEMM (4 waves, counted vmcnt, split-K) -
__global__ void __launch_bounds__(256) gemm_cat(
    const u16* __restrict__ A, const u16* __restrict__ W,
    const float* __restrict__ bias, const float* __restrict__ resid,
    float* __restrict__ Cf, float* __restrict__ Cf1,
    int Kseg, int kslice, int N) {
  __shared__ u16 As[2][128 * 64];
  __shared__ u16 Bs[2][128 * 64];
  const int tid = threadIdx.x;
  const int lane = tid & 63, wv = tid >> 6;
  const int wm = wv >> 1, wn = wv & 1;
  const int pid = blockIdx.y * gridDim.x + blockIdx.x;
  const int cpx = (gridDim.x * gridDim.y) >> 3;
  const int swz = (pid & 7) * cpx + (pid >> 3);
  const int m0 = (swz / gridDim.x) * 128, n0 = (swz % gridDim.x) * 128;
  const int lrow = lane >> 3;
  const int kgS = (lane & 7) ^ lrow;
  const int kv0 = blockIdx.z * kslice;
  const int nt = kslice >> 6;

  f32x4 acc[4][4];
  #pragma unroll
  for (int i = 0; i < 4; ++i)
    #pragma unroll
    for (int j = 0; j < 4; ++j) acc[i][j] = (f32x4){0.f, 0.f, 0.f, 0.f};

  auto STAGE = [&](int kv, int buf) {
    #pragma unroll
    for (int r = 0; r < 4; ++r) {
      int seg = wv * 4 + r;
      int row = seg * 8 + lrow;
      GLDS16(A + (size_t)(m0 + row) * Kseg + kv + kgS * 8, &As[buf][seg * 512]);
      GLDS16(W + (size_t)(n0 + row) * Kseg + kv + kgS * 8, &Bs[buf][seg * 512]);
    }
  };

  STAGE(kv0, 0);
  for (int t = 0; t < nt; ++t) {
    const int cur = t & 1;
    if (t + 1 < nt) {
      STAGE(kv0 + (t + 1) * 64, cur ^ 1);
      asm volatile("s_waitcnt vmcnt(8)" ::: "memory");
    } else {
      asm volatile("s_waitcnt vmcnt(0)" ::: "memory");
    }
    __builtin_amdgcn_s_barrier();
    __builtin_amdgcn_sched_barrier(0);
    #pragma unroll
    for (int kk = 0; kk < 2; ++kk) {
      int kg = kk * 4 + (lane >> 4);
      f16x8 af[4], bf[4];
      #pragma unroll
      for (int mi = 0; mi < 4; ++mi) {
        int row = wm * 64 + mi * 16 + (lane & 15);
        af[mi] = *(const f16x8*)&As[cur][row * 64 + ((kg ^ (row & 7)) << 3)];
      }
      #pragma unroll
      for (int ni = 0; ni < 4; ++ni) {
        int row = wn * 64 + ni * 16 + (lane & 15);
        bf[ni] = *(const f16x8*)&Bs[cur][row * 64 + ((kg ^ (row & 7)) << 3)];
      }
      #pragma unroll
      for (int mi = 0; mi < 4; ++mi)
        #pragma unroll
        for (int ni = 0; ni < 4; ++ni)
          acc[mi][ni] = __builtin_amdgcn_mfma_f32_16x16x32_f16(
              af[mi], bf[ni], acc[mi][ni], 0, 0, 0);
    }
    __builtin_amdgcn_s_barrier();
  }

  const int colb = n0 + wn * 64 + (lane & 15);
  const int rowb = m0 + wm * 64 + ((lane >> 4) << 2);
  const bool z0 = (blockIdx.z == 0);
  float* co = z0 ? Cf : Cf1;
  #pragma unroll
  for (int mi = 0; mi < 4; ++mi) {
    #pragma unroll
    for (int ni = 0; ni < 4; ++ni) {
      int gcol = colb + ni * 16;
      float bv = z0 ? bias[gcol] : 0.f;
      #pragma unroll
      for (int j = 0; j < 4; ++j) {
        int grow = rowb + mi * 16 + j;
        float v = acc[mi][ni][j] + bv;
        size_t o = (size_t)grow * N + gcol;
        if (z0 && resid) v += resid[o];
        co[o] = v;
      }
    }
  }
}

// ---------------- M[b,h,l] = max_u q.k_samp - sum_u(q.k_samp)/L ----------------
__global__ void __launch_bounds__(256) sampled_m(const float* __restrict__ q,
                                                 const float* __restrict__ k,
                                                 const int* __restrict__ idx,
                                                 float* __restrict__ M) {
  const int g = threadIdx.x >> 6, t = threadIdx.x & 63;
  const int bid = blockIdx.x;
  const int c6 = bid & 63;
  const int bh = ((c6 & 7) << 3) | (c6 >> 3);   // bid%8 == bh>>3 fixed per bh
  const int l = (bid >> 6) * 4 + g;
  const int bhl = (bh << 10) | l;
  const float4 qv = *(const float4*)&q[(size_t)bhl * DH + (t & 15) * 4];
  const float* kbase = k + (((size_t)bh) << 10) * DH;
  const int* ip = idx + l * UTOP;
  float vmax = -INFINITY, vsum = 0.f;
  #pragma unroll
  for (int b = 0; b < 9; ++b) {
    int u = b * 4 + (t >> 4);
    bool valid = (u < UTOP);
    int kr = valid ? ip[u] : 0;
    float4 kv = *(const float4*)&kbase[(size_t)kr * DH + (t & 15) * 4];
    float p = qv.x * kv.x + qv.y * kv.y + qv.z * kv.z + qv.w * kv.w;
    p += __shfl_xor(p, 1);
    p += __shfl_xor(p, 2);
    p += __shfl_xor(p, 4);
    p += __shfl_xor(p, 8);
    if (valid) { vmax = fmaxf(vmax, p); vsum += p; }
  }
  vmax = fmaxf(vmax, __shfl_down(vmax, 32));
  vmax = fmaxf(vmax, __shfl_down(vmax, 16));
  vsum += __shfl_down(vsum, 32);
  vsum += __shfl_down(vsum, 16);
  if (t == 0) M[bhl] = vmax - vsum * (1.0f / (float)LSEQ);
}

// ---------------- iterative top-35 per (b,h) ----------------
__global__ void __launch_bounds__(256) topk35(const float* __restrict__ M,
                                              int* __restrict__ top) {
  int bh = blockIdx.x;
  int t = threadIdx.x;
  __shared__ float mv[LSEQ];
  __shared__ float rv[256];
  __shared__ int   ri[256];
  for (int i = t; i < LSEQ; i += 256) mv[i] = M[(size_t)bh * LSEQ + i];
  __syncthreads();
  for (int it = 0; it < UTOP; ++it) {
    float bestv = -INFINITY; int besti = 0x7fffffff;
    for (int i = t; i < LSEQ; i += 256) {
      float v = mv[i];
      if (v > bestv || (v == bestv && i < besti)) { bestv = v; besti = i; }
    }
    rv[t] = bestv; ri[t] = besti;
    __syncthreads();
    for (int s = 128; s; s >>= 1) {
      if (t < s) {
        float v2 = rv[t + s]; int i2 = ri[t + s];
        if (v2 > rv[t] || (v2 == rv[t] && i2 < ri[t])) { rv[t] = v2; ri[t] = i2; }
      }
      __syncthreads();
    }
    if (t == 0) { top[bh * UTOP + it] = ri[0]; mv[ri[0]] = -INFINITY; }
    __syncthreads();
  }
}

// ---------------- vmean[b,h,e] = mean_l v ----------------
__global__ void __launch_bounds__(256) vmean_k(const float* __restrict__ v,
                                               float* __restrict__ vm) {
  int bh = blockIdx.x, t = threadIdx.x;
  int e = t & 63, c = t >> 6;
  float s = 0.f;
  for (int l = c * 256; l < (c + 1) * 256; ++l)
    s += v[((size_t)bh * LSEQ + l) * DH + e];
  __shared__ float pr[4][64];
  pr[c][e] = s; __syncthreads();
  if (t < 64)
    vm[bh * DH + t] = (pr[0][t] + pr[1][t] + pr[2][t] + pr[3][t]) * (1.0f / (float)LSEQ);
}

// ---------------- ctx = vmean broadcast -> ctxh fp16 -------------------------
__global__ void __launch_bounds__(256) ctx_fillb(const float* __restrict__ vm,
                                                 u16* __restrict__ ctxh) {
  int j4 = (blockIdx.x * 256 + threadIdx.x) * 4;   // linear over (b,h,l,e)
  int bh = j4 >> 16;
  int e = j4 & 63;
  float4 v = *(const float4*)&vm[bh * DH + e];
  ushort4 h;
  h.x = f2h(v.x); h.y = f2h(v.y); h.z = f2h(v.z); h.w = f2h(v.w);
  *(ushort4*)&ctxh[(size_t)(j4 >> 9) * 512 + (j4 & 511)] = h;
}

// ---------------- attention partial: 5 rows x 256 keys per block -------------
// Flash-style split-KV: writes unnormalized o, local max m, local sum s.
// grid = 1792: bid -> c6 (XCD-pin) | rest = uc*4 + qtr
__global__ void __launch_bounds__(256) attn_part(const float* __restrict__ q,
                                                 const float* __restrict__ k,
                                                 const float* __restrict__ v,
                                                 const int* __restrict__ top,
                                                 float* __restrict__ pm,
                                                 float* __restrict__ ps,
                                                 float* __restrict__ po) {
  const int bid = blockIdx.x;
  const int c6 = bid & 63;
  const int bh = ((c6 & 7) << 3) | (c6 >> 3);       // XCD-pinning swizzle
  const int rest = bid >> 6;                        // 0..27
  const int uc = rest >> 2, qtr = rest & 3;
  const int k0 = qtr * 256;
  const int t = threadIdx.x;
  const int lane = t & 63, wvi = t >> 6;
  __shared__ float qs[5][DH];
  __shared__ float sc[5][256];
  __shared__ float red[5][4];
  __shared__ float part[4][5][DH];
  __shared__ float mxs[5];
  int rows[5];
  #pragma unroll
  for (int i = 0; i < 5; ++i) rows[i] = top[bh * UTOP + uc * 5 + i];
  for (int i = t; i < 5 * DH; i += 256) {
    int u = i >> 6, e = i & 63;
    qs[u][e] = q[((size_t)bh * LSEQ + rows[u]) * DH + e];
  }
  __syncthreads();

  // pass 1: one key per thread
  const float4* kp = (const float4*)&k[((size_t)bh * LSEQ + k0 + t) * DH];
  float d[5] = {};
  #pragma unroll
  for (int c0 = 0; c0 < 16; c0 += 8) {
    float4 kr[8];
    #pragma unroll
    for (int e = 0; e < 8; ++e) kr[e] = kp[c0 + e];
    #pragma unroll
    for (int u = 0; u < 5; ++u) {
      const float4* q4 = (const float4*)qs[u];
      #pragma unroll
      for (int e = 0; e < 8; ++e) {
        float4 qv = q4[c0 + e];
        d[u] += qv.x * kr[e].x + qv.y * kr[e].y + qv.z * kr[e].z + qv.w * kr[e].w;
      }
    }
  }
  #pragma unroll
  for (int u = 0; u < 5; ++u) {
    float dv = d[u] * 0.125f;
    sc[u][t] = dv;
    float m = dv;
    #pragma unroll
    for (int off = 32; off; off >>= 1) m = fmaxf(m, __shfl_down(m, off));
    if (lane == 0) red[u][wvi] = m;
  }
  __syncthreads();
  if (t < 5)
    mxs[t] = fmaxf(fmaxf(red[t][0], red[t][1]), fmaxf(red[t][2], red[t][3]));
  __syncthreads();

  // pass 2: exp own element + sum
  #pragma unroll
  for (int u = 0; u < 5; ++u) {
    float p = expf(sc[u][t] - mxs[u]);
    sc[u][t] = p;
    #pragma unroll
    for (int off = 32; off; off >>= 1) p += __shfl_down(p, off);
    if (lane == 0) red[u][wvi] = p;
  }
  __syncthreads();

  // pass 3: PV over 64 keys per wave-chunk
  int e = t & 63, cq = t >> 6;
  float acc[5] = {};
  for (int kk = cq * 64; kk < (cq + 1) * 64; ++kk) {
    float vv = v[((size_t)bh * LSEQ + k0 + kk) * DH + e];
    #pragma unroll
    for (int u = 0; u < 5; ++u) acc[u] += sc[u][kk] * vv;
  }
  #pragma unroll
  for (int u = 0; u < 5; ++u) part[cq][u][e] = acc[u];
  __syncthreads();

  const int slot = (bh * 7 + uc) * 4 + qtr;
  if (t < 5) {
    pm[slot * 5 + t] = mxs[t];
    ps[slot * 5 + t] = red[t][0] + red[t][1] + red[t][2] + red[t][3];
  }
  for (int i = t; i < 5 * DH; i += 256) {
    int u = i >> 6, ee = i & 63;
    po[((size_t)slot * 5 + u) * 64 + ee] =
        part[0][u][ee] + part[1][u][ee] + part[2][u][ee] + part[3][u][ee];
  }
}

// ---------------- merge 4 partials -> ctxh (selected rows) -------------------
__global__ void __launch_bounds__(256) attn_merge(const float* __restrict__ pm,
                                                  const float* __restrict__ ps,
                                                  const float* __restrict__ po,
                                                  const int* __restrict__ top,
                                                  u16* __restrict__ ctxh) {
  const int bid = blockIdx.x;                        // 448
  const int c6 = bid & 63, uc = bid >> 6;
  const int bh = ((c6 & 7) << 3) | (c6 >> 3);
  const int t = threadIdx.x;
  const int base = (bh * 7 + uc) * 4;
  __shared__ float wgt[5][4];
  __shared__ float inv[5];
  __shared__ int rows[5];
  if (t < 5) {
    rows[t] = top[bh * UTOP + uc * 5 + t];
    float m0 = pm[(base + 0) * 5 + t], m1 = pm[(base + 1) * 5 + t];
    float m2 = pm[(base + 2) * 5 + t], m3 = pm[(base + 3) * 5 + t];
    float M = fmaxf(fmaxf(m0, m1), fmaxf(m2, m3));
    float w0 = expf(m0 - M), w1 = expf(m1 - M);
    float w2 = expf(m2 - M), w3 = expf(m3 - M);
    float S = ps[(base + 0) * 5 + t] * w0 + ps[(base + 1) * 5 + t] * w1 +
              ps[(base + 2) * 5 + t] * w2 + ps[(base + 3) * 5 + t] * w3;
    wgt[t][0] = w0; wgt[t][1] = w1; wgt[t][2] = w2; wgt[t][3] = w3;
    inv[t] = 1.0f / S;
  }
  __syncthreads();
  for (int i = t; i < 5 * DH; i += 256) {
    int u = i >> 6, e = i & 63;
    float o = po[((size_t)(base + 0) * 5 + u) * 64 + e] * wgt[u][0] +
              po[((size_t)(base + 1) * 5 + u) * 64 + e] * wgt[u][1] +
              po[((size_t)(base + 2) * 5 + u) * 64 + e] * wgt[u][2] +
              po[((size_t)(base + 3) * 5 + u) * 64 + e] * wgt[u][3];
    float s = o * inv[u];
    size_t lin = ((size_t)bh * LSEQ + rows[u]) * DH + e;
    ctxh[(lin >> 9) * 512 + (lin & 511)] = f2h(s);
  }
}

// ---------------- layernorm over D=512 (in [+ in2]); fp32 out + fp16 xh ----
__global__ void __launch_bounds__(256) ln_k(const float* __restrict__ in,
                                            const float* __restrict__ in2,
                                            const float* __restrict__ g,
                                            const float* __restrict__ be,
                                            float* __restrict__ out,
                                            u16* __restrict__ oh,
                                            const float* __restrict__ mark) {
  int row = blockIdx.x, t = threadIdx.x;
  size_t o0 = (size_t)row * DMODEL + t, o1 = o0 + 256;
  float x0 = in[o0], x1 = in[o1];
  if (in2) { x0 += in2[o0]; x1 += in2[o1]; }
  __shared__ float red[256];
  red[t] = x0 + x1; __syncthreads();
  for (int s = 128; s; s >>= 1) { if (t < s) red[t] += red[t + s]; __syncthreads(); }
  float mean = red[0] * (1.0f / DMODEL);
  __syncthreads();
  float d0 = x0 - mean, d1 = x1 - mean;
  red[t] = d0 * d0 + d1 * d1; __syncthreads();
  for (int s = 128; s; s >>= 1) { if (t < s) red[t] += red[t + s]; __syncthreads(); }
  float rstd = 1.0f / sqrtf(red[0] * (1.0f / DMODEL) + 1e-5f);
  float v0 = d0 * rstd * g[t] + be[t];
  float v1 = d1 * rstd * g[t + 256] + be[t + 256];
  if (mark) { float mk = mark[row]; v0 *= mk; v1 *= mk; }
  if (out) { out[o0] = v0; out[o1] = v1; }
  if (oh) {
    oh[o0] = f2h(v0);
    oh[o1] = f2h(v1);
  }
}

// ---------------- final fc: split-K two-stage ----------------
__global__ void __launch_bounds__(256) fc_stage1(const float* __restrict__ y,
                                                 const float* __restrict__ fw,
                                                 float* __restrict__ part) {
  int blk = blockIdx.x;
  int k0 = blk * 1024;
  int tid = threadIdx.x;
  __shared__ float ys[NB][1024];
  #pragma unroll
  for (int b = 0; b < NB; ++b)
    *(float4*)&ys[b][tid * 4] = *(const float4*)&y[(size_t)b * (LSEQ * DMODEL) + k0 + tid * 4];
  __syncthreads();
  int c = tid & 15, ks = tid >> 4;
  float acc[NB] = {};
  const float* wp = fw + (size_t)c * (LSEQ * DMODEL) + k0 + ks * 64;
  for (int j = 0; j < 16; ++j) {
    int jj = (j + ks) & 15;
    float4 w4 = *(const float4*)&wp[jj * 4];
    #pragma unroll
    for (int b = 0; b < NB; ++b) {
      float4 yv = *(const float4*)&ys[b][ks * 64 + jj * 4];
      acc[b] += yv.x * w4.x + yv.y * w4.y + yv.z * w4.z + yv.w * w4.w;
    }
  }
  __shared__ float rs[16][128];
  #pragma unroll
  for (int b = 0; b < NB; ++b) rs[ks][b * 16 + c] = acc[b];
  __syncthreads();
  if (tid < 128) {
    float s = 0.f;
    #pragma unroll
    for (int i = 0; i < 16; ++i) s += rs[i][tid];
    part[(size_t)tid * 512 + blk] = s;
  }
}

__global__ void __launch_bounds__(128) fc_stage2(const float* __restrict__ part,
                                                 const float* __restrict__ fb,
                                                 float* __restrict__ out) {
  int bc = threadIdx.x;
  float s = 0.f;
  for (int i = 0; i < 512; ++i) s += part[(size_t)bc * 512 + i];
  out[bc] = s + fb[bc & 15];
}

// ---------------- host launch ----------------
extern "C" void kernel_launch(void* const* d_in, const int* in_sizes, int n_in,
                              void* d_out, int out_size, void* d_ws, size_t ws_size,
                              hipStream_t stream) {
  (void)in_sizes; (void)n_in; (void)out_size; (void)ws_size;
  const float* x_enc  = (const float*)d_in[0];
  const float* x_mark = (const float*)d_in[1];
  const float* conv_w = (const float*)d_in[2];
  const float* Wq = (const float*)d_in[3];
  const float* bq = (const float*)d_in[4];
  const float* Wk = (const float*)d_in[5];
  const float* bk = (const float*)d_in[6];
  const float* Wv = (const float*)d_in[7];
  const float* bv = (const float*)d_in[8];
  const float* Wo = (const float*)d_in[9];
  const float* bo = (const float*)d_in[10];
  const float* W1 = (const float*)d_in[11];
  const float* b1 = (const float*)d_in[12];
  const float* W2 = (const float*)d_in[13];
  const float* b2 = (const float*)d_in[14];
  const float* g1 = (const float*)d_in[15];
  const float* be1= (const float*)d_in[16];
  const float* g2 = (const float*)d_in[17];
  const float* be2= (const float*)d_in[18];
  const float* gF = (const float*)d_in[19];
  const float* bF = (const float*)d_in[20];
  const float* fcw= (const float*)d_in[21];
  const float* fcb= (const float*)d_in[22];
  float* out = (float*)d_out;

  const size_t NBLD = (size_t)NB * LSEQ * DMODEL;       // 4,194,304
  float* ws   = (float*)d_ws;
  float* xb   = ws;                    // residual fp32
  float* pre0 = xb   + NBLD;           // pre-LN fp32
  float* qb   = pre0 + NBLD;           // q fp32; later preB; later hidh (with kb)
  float* kb   = qb   + NBLD;
  float* vb   = kb   + NBLD;           // v fp32; later preC
  u16*  xh    = (u16*)(vb + NBLD);     // NBLD u16
  u16*  ctxh  = xh + NBLD;             // NBLD u16
  u16*  Wcat  = ctxh + NBLD;           // fp16 weights, all layers (9,437,184 u16)
  float* Mb   = (float*)(Wcat + (size_t)NLAYER * WPERL);
  float* vm   = Mb + (size_t)NB * NH * LSEQ;
  float* part = vm + NB * NH * DH;
  int* idxb   = (int*)(part + 512 * 128);
  int* topb   = idxb + LSEQ * UTOP;
  float* pmb  = (float*)(topb + NB * NH * UTOP);   // 1792*5
  float* psb  = pmb + 1792 * 5;                    // 1792*5
  float* pob  = psb + 1792 * 5;                    // 1792*5*64 = 573,440
  u16* hidh   = (u16*)qb;              // 8192 x 2048 u16 == [qb|kb] exactly
  float* preB = qb;                    // Wo slice-1 partial (q dead by then)
  float* preC = vb;                    // W2 slice-1 partial (v dead by then)

  // all weights -> fp16, one dispatch
  cvt_all<<<2048, 256, 0, stream>>>(Wq, Wk, Wv, Wo, W1, W2, Wcat);

  {
    dim3 gc(8, 32, NB);
    conv_pe<<<gc, 256, 0, stream>>>(x_enc, conv_w, xb, xh);
  }

  dim3 gqkv(6,  32);       // 256x256 tiles: N=1536, K=512 (nt=8), 192 blocks
  dim3 gw1 (8,  32);       // 256x256 tiles: N=2048, K=512 (nt=8), 256 blocks
  dim3 gwo (4,  64, 2);    // 128 tiles, K=512 split-K 2 (kslice 256, nt=4)
  dim3 gw2 (4,  64, 2);    // 128 tiles, K=2048 split-K 2 (kslice 1024, nt=16)

  for (int l = 0; l < NLAYER; ++l) {
    const u16* Wl    = Wcat + (size_t)l * WPERL;
    const u16* Wc_qkv= Wl;                   // 1536 x 512
    const u16* Wc_o  = Wl + 786432;          //  512 x 512
    const u16* Wc_1  = Wl + 1048576;         // 2048 x 512
    const u16* Wc_2  = Wl + 2097152;         //  512 x 2048

    // fused QKV (mode 3) -> qb/kb/vb
    gemm256<<<gqkv, 512, 0, stream>>>(xh, Wc_qkv,
                                      bq + l*DMODEL, bk + l*DMODEL, bv + l*DMODEL,
                                      qb, nullptr, 512, 1536, 3);

    // prob-attention
    uint32_t lk0, lk1, k2_0, k2_1;
    tf2x32(0u, 42u, 0u, (uint32_t)l, lk0, lk1);
    tf2x32(lk0, lk1, 0u, 1u, k2_0, k2_1);
    gen_idx_kernel<<<140, 256, 0, stream>>>(k2_0, k2_1, idxb);
    sampled_m<<<NB * NH * LSEQ / 4, 256, 0, stream>>>(qb, kb, idxb, Mb);
    topk35<<<NB * NH, 256, 0, stream>>>(Mb, topb);
    vmean_k<<<NB * NH, 256, 0, stream>>>(vb, vm);
    ctx_fillb<<<(NB * NH * LSEQ * DH) / 1024, 256, 0, stream>>>(vm, ctxh);
    attn_part<<<1792, 256, 0, stream>>>(qb, kb, vb, topb, pmb, psb, pob);
    attn_merge<<<448, 256, 0, stream>>>(pmb, psb, pob, topb, ctxh);

    // Wo (+resid xb), split-K 2 -> pre0 / preB ; LN1 -> xb + xh
    gemm_cat<<<gwo, 256, 0, stream>>>(ctxh, Wc_o, bo + l*DMODEL,
                                      xb, pre0, preB, 512, 256, 512);
    ln_k<<<NB * LSEQ, 256, 0, stream>>>(pre0, preB, g1 + l*DMODEL, be1 + l*DMODEL,
                                        xb, xh, nullptr);

    // FFN: W1 relu -> hidh fp16; W2 split-K 2 -> pre0/preC; LN2
    gemm256<<<gw1, 512, 0, stream>>>(xh, Wc_1,
                                     b1 + l*DFF, nullptr, nullptr,
                                     nullptr, hidh, 512, 2048, 1);
    gemm_cat<<<gw2, 256, 0, stream>>>(hidh, Wc_2, b2 + l*DMODEL,
                                      xb, pre0, preC, 2048, 1024, 512);
    ln_k<<<NB * LSEQ, 256, 0, stream>>>(pre0, preC, g2 + l*DMODEL, be2 + l*DMODEL,
                                        xb, xh, nullptr);
  }

  // final LN (*mark) -> pre0 ; split-K fc
  ln_k<<<NB * LSEQ, 256, 0, stream>>>(xb, nullptr, gF, bF, pre0, nullptr, x_mark);
  fc_stage1<<<512, 256, 0, stream>>>(pre0, fcw, part);
  fc_stage2<<<1, 128, 0, stream>>>(part, fcb, out);
}

// Round 14
// 969.899 us; speedup vs baseline: 1.0488x; 1.0488x over previous
//
#include <hip/hip_runtime.h>
#include <stdint.h>
#include <math.h>

// ---------------- problem constants ----------------
#define LSEQ   1024
#define DMODEL 512
#define NH     8
#define DH     64
#define DFF    2048
#define NB     8
#define NLAYER 3
#define UTOP   35
#define NCLS   16
#define WPERL  3145728   // fp16 weight elements per layer: [Wq|Wk|Wv|Wo|W1|W2]

typedef unsigned short u16;
typedef _Float16 f16x8 __attribute__((ext_vector_type(8)));
typedef __attribute__((ext_vector_type(4))) float f32x4;

// fp16 helpers (RNE)
__device__ __forceinline__ u16 f2h(float f) {
  _Float16 h = (_Float16)f;
  return __builtin_bit_cast(u16, h);
}
__device__ __forceinline__ float h2f(u16 b) {
  return (float)__builtin_bit_cast(_Float16, b);
}

#define GLDS16(gsrc, ldst)                                                        \
  __builtin_amdgcn_global_load_lds(                                              \
      (const __attribute__((address_space(1))) void*)(gsrc),                     \
      (__attribute__((address_space(3))) void*)(ldst), 16, 0, 0)

// ---------------- threefry2x32 (exact JAX semantics) ----------------
__host__ __device__ __forceinline__ uint32_t rotl32(uint32_t x, int d) {
  return (x << d) | (x >> (32 - d));
}
__host__ __device__ inline void tf2x32(uint32_t k0, uint32_t k1,
                                       uint32_t c0, uint32_t c1,
                                       uint32_t& o0, uint32_t& o1) {
  uint32_t ks2 = k0 ^ k1 ^ 0x1BD11BDAu;
  uint32_t x0 = c0 + k0, x1 = c1 + k1;
#define TF_R4(a,b,c,d) \
  x0 += x1; x1 = rotl32(x1,(a)); x1 ^= x0; \
  x0 += x1; x1 = rotl32(x1,(b)); x1 ^= x0; \
  x0 += x1; x1 = rotl32(x1,(c)); x1 ^= x0; \
  x0 += x1; x1 = rotl32(x1,(d)); x1 ^= x0;
  TF_R4(13,15,26,6)   x0 += k1;  x1 += ks2 + 1u;
  TF_R4(17,29,16,24)  x0 += ks2; x1 += k0 + 2u;
  TF_R4(13,15,26,6)   x0 += k0;  x1 += k1 + 3u;
  TF_R4(17,29,16,24)  x0 += k1;  x1 += ks2 + 4u;
  TF_R4(13,15,26,6)   x0 += ks2; x1 += k0 + 5u;
#undef TF_R4
  o0 = x0; o1 = x1;
}

__global__ void __launch_bounds__(256) gen_idx_kernel(uint32_t k0, uint32_t k1,
                                                      int* idx) {
  int i = blockIdx.x * 256 + threadIdx.x;
  if (i >= LSEQ * UTOP) return;
  uint32_t a, b;
  tf2x32(k0, k1, 0u, (uint32_t)i, a, b);
  idx[i] = (int)((a ^ b) & (LSEQ - 1));
}

// ---------------- ALL weights fp32 -> fp16, one dispatch ----------------
__global__ void __launch_bounds__(256) cvt_all(
    const float* __restrict__ Wq, const float* __restrict__ Wk,
    const float* __restrict__ Wv, const float* __restrict__ Wo,
    const float* __restrict__ W1, const float* __restrict__ W2,
    u16* __restrict__ dst) {
  const size_t total = (size_t)NLAYER * WPERL;
  for (size_t i4 = ((size_t)blockIdx.x * 256 + threadIdx.x) * 4;
       i4 < total; i4 += (size_t)gridDim.x * 256 * 4) {
    int l = (int)(i4 / WPERL);
    int off = (int)(i4 % WPERL);
    const float* src; size_t so;
    if (off < 262144)       { src = Wq; so = (size_t)l * 262144  + off; }
    else if (off < 524288)  { src = Wk; so = (size_t)l * 262144  + off - 262144; }
    else if (off < 786432)  { src = Wv; so = (size_t)l * 262144  + off - 524288; }
    else if (off < 1048576) { src = Wo; so = (size_t)l * 262144  + off - 786432; }
    else if (off < 2097152) { src = W1; so = (size_t)l * 1048576 + off - 1048576; }
    else                    { src = W2; so = (size_t)l * 1048576 + off - 2097152; }
    float4 v = *(const float4*)&src[so];
    ushort4 h;
    h.x = f2h(v.x); h.y = f2h(v.y); h.z = f2h(v.z); h.w = f2h(v.w);
    *(ushort4*)&dst[i4] = h;
  }
}

// ---------------- conv1d (circular pad 1) + PE, batch-parallel ----------------
__global__ void __launch_bounds__(256) conv_pe(const float* __restrict__ xe,
                                               const float* __restrict__ w,
                                               float* __restrict__ xout,
                                               u16* __restrict__ xh) {
  const int d0 = blockIdx.x * 64;
  const int l0 = blockIdx.y * 32;
  const int b  = blockIdx.z;
  const int tid = threadIdx.x;
  const int dl = tid & 63;
  const int lq = tid >> 6;
  __shared__ float ws_[64][97];
  __shared__ float xs[32][37];

  for (int i = tid; i < 64 * 96; i += 256) {
    int dd = i / 96, cc = i - dd * 96;
    ws_[dd][cc] = w[(size_t)(d0 + dd) * 96 + cc];
  }
  for (int i = tid; i < 34 * 32; i += 256) {
    int r = i >> 5, c = i & 31;
    int row = (l0 - 1 + r + LSEQ) & (LSEQ - 1);
    xs[c][r] = xe[((size_t)b * LSEQ + row) * 32 + c];
  }

  const int d = d0 + dl;
  float div = expf((float)(d & ~1) * (-9.210340371976184f / 512.0f));
  float pe[8];
  #pragma unroll
  for (int j = 0; j < 8; ++j) {
    float arg = (float)(l0 + lq * 8 + j) * div;
    pe[j] = (d & 1) ? cosf(arg) : sinf(arg);
  }
  __syncthreads();

  float acc[8] = {};
  #pragma unroll 4
  for (int c = 0; c < 32; ++c) {
    float w0 = ws_[dl][c * 3 + 0];
    float w1 = ws_[dl][c * 3 + 1];
    float w2 = ws_[dl][c * 3 + 2];
    float xv[10];
    #pragma unroll
    for (int r = 0; r < 10; ++r) xv[r] = xs[c][lq * 8 + r];
    #pragma unroll
    for (int j = 0; j < 8; ++j)
      acc[j] += xv[j] * w0 + xv[j + 1] * w1 + xv[j + 2] * w2;
  }
  #pragma unroll
  for (int j = 0; j < 8; ++j) {
    int l = l0 + lq * 8 + j;
    float v = acc[j] + pe[j];
    size_t m = (size_t)b * LSEQ + l;
    xout[m * DMODEL + d] = v;
    xh[m * DMODEL + d] = f2h(v);
  }
}

// ---------------- 256x256-tile plain-fp16 GEMM (8 waves, counted vmcnt) ------
__global__ void __launch_bounds__(512, 2) gemm256(
    const u16* __restrict__ A, const u16* __restrict__ W,
    const float* __restrict__ bias, const float* __restrict__ bias_k,
    const float* __restrict__ bias_v,
    float* __restrict__ Cf, u16* __restrict__ C2,
    int Kseg, int N, int mode) {
  __shared__ u16 As[2][256 * 64];
  __shared__ u16 Bs[2][256 * 64];
  const int tid = threadIdx.x;
  const int lane = tid & 63, wv = tid >> 6;     // 8 waves
  const int wm = wv >> 2, wn = wv & 3;          // 2 x 4
  const int pid = blockIdx.y * gridDim.x + blockIdx.x;
  const int cpx = (gridDim.x * gridDim.y) >> 3;
  const int swz = (pid & 7) * cpx + (pid >> 3);
  const int m0 = (swz / gridDim.x) * 256, n0 = (swz % gridDim.x) * 256;
  const int lrow = lane >> 3;
  const int kgS = (lane & 7) ^ lrow;
  const int nt = Kseg >> 6;

  f32x4 acc[8][4];
  #pragma unroll
  for (int i = 0; i < 8; ++i)
    #pragma unroll
    for (int j = 0; j < 4; ++j) acc[i][j] = (f32x4){0.f, 0.f, 0.f, 0.f};

  auto STAGE = [&](int kv, int buf) {
    #pragma unroll
    for (int r = 0; r < 4; ++r) {
      int seg = wv * 4 + r;
      int row = seg * 8 + lrow;
      GLDS16(A + (size_t)(m0 + row) * Kseg + kv + kgS * 8, &As[buf][seg * 512]);
      GLDS16(W + (size_t)(n0 + row) * Kseg + kv + kgS * 8, &Bs[buf][seg * 512]);
    }
  };

  STAGE(0, 0);
  for (int t = 0; t < nt; ++t) {
    const int cur = t & 1;
    if (t + 1 < nt) {
      STAGE((t + 1) * 64, cur ^ 1);
      asm volatile("s_waitcnt vmcnt(8)" ::: "memory");
    } else {
      asm volatile("s_waitcnt vmcnt(0)" ::: "memory");
    }
    __builtin_amdgcn_s_barrier();
    __builtin_amdgcn_sched_barrier(0);
    #pragma unroll
    for (int kk = 0; kk < 2; ++kk) {
      int kg = kk * 4 + (lane >> 4);
      f16x8 af[8], bf[4];
      #pragma unroll
      for (int mi = 0; mi < 8; ++mi) {
        int row = wm * 128 + mi * 16 + (lane & 15);
        af[mi] = *(const f16x8*)&As[cur][row * 64 + ((kg ^ (row & 7)) << 3)];
      }
      #pragma unroll
      for (int ni = 0; ni < 4; ++ni) {
        int row = wn * 64 + ni * 16 + (lane & 15);
        bf[ni] = *(const f16x8*)&Bs[cur][row * 64 + ((kg ^ (row & 7)) << 3)];
      }
      #pragma unroll
      for (int mi = 0; mi < 8; ++mi)
        #pragma unroll
        for (int ni = 0; ni < 4; ++ni)
          acc[mi][ni] = __builtin_amdgcn_mfma_f32_16x16x32_f16(
              af[mi], bf[ni], acc[mi][ni], 0, 0, 0);
    }
    __builtin_amdgcn_s_barrier();
  }

  const int colb = n0 + wn * 64 + (lane & 15);
  const int rowb = m0 + wm * 128 + ((lane >> 4) << 2);
  #pragma unroll
  for (int mi = 0; mi < 8; ++mi) {
    #pragma unroll
    for (int ni = 0; ni < 4; ++ni) {
      int gcol = colb + ni * 16;
      float bv;
      if (mode == 3) {
        int mat = gcol >> 9, c = gcol & 511;
        bv = (mat == 0 ? bias : (mat == 1 ? bias_k : bias_v))[c];
      } else {
        bv = bias[gcol];
      }
      #pragma unroll
      for (int j = 0; j < 4; ++j) {
        int grow = rowb + mi * 16 + j;
        float v = acc[mi][ni][j] + bv;
        if (mode == 1) {
          C2[(size_t)grow * N + gcol] = f2h(fmaxf(v, 0.f));
        } else {  // 3: fused QKV scatter
          int mat = gcol >> 9, c = gcol & 511;
          Cf[(size_t)mat * (NB * LSEQ * DMODEL) +
             (size_t)(grow >> 10) * (NH * LSEQ * DH) +
             (size_t)(c >> 6) * (LSEQ * DH) +
             (size_t)(grow & (LSEQ - 1)) * DH + (c & (DH - 1))] = v;
        }
      }
    }
  }
}

// ---------------- 128-tile plain-fp16 GEMM (4 waves, counted vmcnt, split-K) -
__global__ void __launch_bounds__(256) gemm_cat(
    const u16* __restrict__ A, const u16* __restrict__ W,
    const float* __restrict__ bias, const float* __restrict__ resid,
    float* __restrict__ Cf, float* __restrict__ Cf1,
    int Kseg, int kslice, int N) {
  __shared__ u16 As[2][128 * 64];
  __shared__ u16 Bs[2][128 * 64];
  const int tid = threadIdx.x;
  const int lane = tid & 63, wv = tid >> 6;
  const int wm = wv >> 1, wn = wv & 1;
  const int pid = blockIdx.y * gridDim.x + blockIdx.x;
  const int cpx = (gridDim.x * gridDim.y) >> 3;
  const int swz = (pid & 7) * cpx + (pid >> 3);
  const int m0 = (swz / gridDim.x) * 128, n0 = (swz % gridDim.x) * 128;
  const int lrow = lane >> 3;
  const int kgS = (lane & 7) ^ lrow;
  const int kv0 = blockIdx.z * kslice;
  const int nt = kslice >> 6;

  f32x4 acc[4][4];
  #pragma unroll
  for (int i = 0; i < 4; ++i)
    #pragma unroll
    for (int j = 0; j < 4; ++j) acc[i][j] = (f32x4){0.f, 0.f, 0.f, 0.f};

  auto STAGE = [&](int kv, int buf) {
    #pragma unroll
    for (int r = 0; r < 4; ++r) {
      int seg = wv * 4 + r;
      int row = seg * 8 + lrow;
      GLDS16(A + (size_t)(m0 + row) * Kseg + kv + kgS * 8, &As[buf][seg * 512]);
      GLDS16(W + (size_t)(n0 + row) * Kseg + kv + kgS * 8, &Bs[buf][seg * 512]);
    }
  };

  STAGE(kv0, 0);
  for (int t = 0; t < nt; ++t) {
    const int cur = t & 1;
    if (t + 1 < nt) {
      STAGE(kv0 + (t + 1) * 64, cur ^ 1);
      asm volatile("s_waitcnt vmcnt(8)" ::: "memory");
    } else {
      asm volatile("s_waitcnt vmcnt(0)" ::: "memory");
    }
    __builtin_amdgcn_s_barrier();
    __builtin_amdgcn_sched_barrier(0);
    #pragma unroll
    for (int kk = 0; kk < 2; ++kk) {
      int kg = kk * 4 + (lane >> 4);
      f16x8 af[4], bf[4];
      #pragma unroll
      for (int mi = 0; mi < 4; ++mi) {
        int row = wm * 64 + mi * 16 + (lane & 15);
        af[mi] = *(const f16x8*)&As[cur][row * 64 + ((kg ^ (row & 7)) << 3)];
      }
      #pragma unroll
      for (int ni = 0; ni < 4; ++ni) {
        int row = wn * 64 + ni * 16 + (lane & 15);
        bf[ni] = *(const f16x8*)&Bs[cur][row * 64 + ((kg ^ (row & 7)) << 3)];
      }
      #pragma unroll
      for (int mi = 0; mi < 4; ++mi)
        #pragma unroll
        for (int ni = 0; ni < 4; ++ni)
          acc[mi][ni] = __builtin_amdgcn_mfma_f32_16x16x32_f16(
              af[mi], bf[ni], acc[mi][ni], 0, 0, 0);
    }
    __builtin_amdgcn_s_barrier();
  }

  const int colb = n0 + wn * 64 + (lane & 15);
  const int rowb = m0 + wm * 64 + ((lane >> 4) << 2);
  const bool z0 = (blockIdx.z == 0);
  float* co = z0 ? Cf : Cf1;
  #pragma unroll
  for (int mi = 0; mi < 4; ++mi) {
    #pragma unroll
    for (int ni = 0; ni < 4; ++ni) {
      int gcol = colb + ni * 16;
      float bv = z0 ? bias[gcol] : 0.f;
      #pragma unroll
      for (int j = 0; j < 4; ++j) {
        int grow = rowb + mi * 16 + j;
        float v = acc[mi][ni][j] + bv;
        size_t o = (size_t)grow * N + gcol;
        if (z0 && resid) v += resid[o];
        co[o] = v;
      }
    }
  }
}

// ---------------- M[b,h,l] = max_u q.k_samp - sum_u(q.k_samp)/L ----------------
__global__ void __launch_bounds__(256) sampled_m(const float* __restrict__ q,
                                                 const float* __restrict__ k,
                                                 const int* __restrict__ idx,
                                                 float* __restrict__ M) {
  const int g = threadIdx.x >> 6, t = threadIdx.x & 63;
  const int bid = blockIdx.x;
  const int c6 = bid & 63;
  const int bh = ((c6 & 7) << 3) | (c6 >> 3);   // bid%8 == bh>>3 fixed per bh
  const int l = (bid >> 6) * 4 + g;
  const int bhl = (bh << 10) | l;
  const float4 qv = *(const float4*)&q[(size_t)bhl * DH + (t & 15) * 4];
  const float* kbase = k + (((size_t)bh) << 10) * DH;
  const int* ip = idx + l * UTOP;
  float vmax = -INFINITY, vsum = 0.f;
  #pragma unroll
  for (int b = 0; b < 9; ++b) {
    int u = b * 4 + (t >> 4);
    bool valid = (u < UTOP);
    int kr = valid ? ip[u] : 0;
    float4 kv = *(const float4*)&kbase[(size_t)kr * DH + (t & 15) * 4];
    float p = qv.x * kv.x + qv.y * kv.y + qv.z * kv.z + qv.w * kv.w;
    p += __shfl_xor(p, 1);
    p += __shfl_xor(p, 2);
    p += __shfl_xor(p, 4);
    p += __shfl_xor(p, 8);
    if (valid) { vmax = fmaxf(vmax, p); vsum += p; }
  }
  vmax = fmaxf(vmax, __shfl_down(vmax, 32));
  vmax = fmaxf(vmax, __shfl_down(vmax, 16));
  vsum += __shfl_down(vsum, 32);
  vsum += __shfl_down(vsum, 16);
  if (t == 0) M[bhl] = vmax - vsum * (1.0f / (float)LSEQ);
}

// ---------------- iterative top-35 per (b,h) ----------------
__global__ void __launch_bounds__(256) topk35(const float* __restrict__ M,
                                              int* __restrict__ top) {
  int bh = blockIdx.x;
  int t = threadIdx.x;
  __shared__ float mv[LSEQ];
  __shared__ float rv[256];
  __shared__ int   ri[256];
  for (int i = t; i < LSEQ; i += 256) mv[i] = M[(size_t)bh * LSEQ + i];
  __syncthreads();
  for (int it = 0; it < UTOP; ++it) {
    float bestv = -INFINITY; int besti = 0x7fffffff;
    for (int i = t; i < LSEQ; i += 256) {
      float v = mv[i];
      if (v > bestv || (v == bestv && i < besti)) { bestv = v; besti = i; }
    }
    rv[t] = bestv; ri[t] = besti;
    __syncthreads();
    for (int s = 128; s; s >>= 1) {
      if (t < s) {
        float v2 = rv[t + s]; int i2 = ri[t + s];
        if (v2 > rv[t] || (v2 == rv[t] && i2 < ri[t])) { rv[t] = v2; ri[t] = i2; }
      }
      __syncthreads();
    }
    if (t == 0) { top[bh * UTOP + it] = ri[0]; mv[ri[0]] = -INFINITY; }
    __syncthreads();
  }
}

// ---------------- vmean[b,h,e] = mean_l v ----------------
__global__ void __launch_bounds__(256) vmean_k(const float* __restrict__ v,
                                               float* __restrict__ vm) {
  int bh = blockIdx.x, t = threadIdx.x;
  int e = t & 63, c = t >> 6;
  float s = 0.f;
  for (int l = c * 256; l < (c + 1) * 256; ++l)
    s += v[((size_t)bh * LSEQ + l) * DH + e];
  __shared__ float pr[4][64];
  pr[c][e] = s; __syncthreads();
  if (t < 64)
    vm[bh * DH + t] = (pr[0][t] + pr[1][t] + pr[2][t] + pr[3][t]) * (1.0f / (float)LSEQ);
}

// ---------------- ctx = vmean broadcast -> ctxh fp16 -------------------------
__global__ void __launch_bounds__(256) ctx_fillb(const float* __restrict__ vm,
                                                 u16* __restrict__ ctxh) {
  int j4 = (blockIdx.x * 256 + threadIdx.x) * 4;   // linear over (b,h,l,e)
  int bh = j4 >> 16;
  int e = j4 & 63;
  float4 v = *(const float4*)&vm[bh * DH + e];
  ushort4 h;
  h.x = f2h(v.x); h.y = f2h(v.y); h.z = f2h(v.z); h.w = f2h(v.w);
  *(ushort4*)&ctxh[(size_t)(j4 >> 9) * 512 + (j4 & 511)] = h;
}

// ---------------- attention partial: 5 rows x 256 keys per block -------------
// Pass 1 uses 16-lane-cooperative coalesced K reads (sampled_m pattern):
// a wave's 4 groups read 4 CONSECUTIVE rows -> 1KB contiguous per instruction.
__global__ void __launch_bounds__(256) attn_part(const float* __restrict__ q,
                                                 const float* __restrict__ k,
                                                 const float* __restrict__ v,
                                                 const int* __restrict__ top,
                                                 float* __restrict__ pm,
                                                 float* __restrict__ ps,
                                                 float* __restrict__ po) {
  const int bid = blockIdx.x;
  const int c6 = bid & 63;
  const int bh = ((c6 & 7) << 3) | (c6 >> 3);       // XCD-pinning swizzle
  const int rest = bid >> 6;                        // 0..27
  const int uc = rest >> 2, qtr = rest & 3;
  const int k0 = qtr * 256;
  const int t = threadIdx.x;
  const int lane = t & 63, wvi = t >> 6;
  const int gl = t & 15;                            // lane in 16-group
  const int gr = t >> 4;                            // group 0..15
  __shared__ float qs[5][DH];
  __shared__ float sc[5][256];
  __shared__ float red[5][4];
  __shared__ float part[4][5][DH];
  __shared__ float mxs[5];
  int rows[5];
  #pragma unroll
  for (int i = 0; i < 5; ++i) rows[i] = top[bh * UTOP + uc * 5 + i];
  for (int i = t; i < 5 * DH; i += 256) {
    int u = i >> 6, e = i & 63;
    qs[u][e] = q[((size_t)bh * LSEQ + rows[u]) * DH + e];
  }
  __syncthreads();

  // pass 1: 16 iterations, each group handles one row per iteration
  float qv[5][4];
  #pragma unroll
  for (int u = 0; u < 5; ++u) {
    float4 qq = ((const float4*)qs[u])[gl];
    qv[u][0] = qq.x; qv[u][1] = qq.y; qv[u][2] = qq.z; qv[u][3] = qq.w;
  }
  float mloc[5] = {-INFINITY, -INFINITY, -INFINITY, -INFINITY, -INFINITY};
  #pragma unroll 4
  for (int it = 0; it < 16; ++it) {
    int kk = it * 16 + gr;                         // wave reads 4 consecutive rows
    float4 kv = ((const float4*)&k[((size_t)bh * LSEQ + k0 + kk) * DH])[gl];
    #pragma unroll
    for (int u = 0; u < 5; ++u) {
      float p = qv[u][0] * kv.x + qv[u][1] * kv.y + qv[u][2] * kv.z + qv[u][3] * kv.w;
      p += __shfl_xor(p, 1);
      p += __shfl_xor(p, 2);
      p += __shfl_xor(p, 4);
      p += __shfl_xor(p, 8);                       // all 16 lanes hold row dot
      float dv = p * 0.125f;
      if (gl == 0) sc[u][kk] = dv;
      mloc[u] = fmaxf(mloc[u], dv);
    }
  }
  #pragma unroll
  for (int u = 0; u < 5; ++u) {
    float m = mloc[u];
    m = fmaxf(m, __shfl_down(m, 32));
    m = fmaxf(m, __shfl_down(m, 16));              // groups within wave
    if (lane == 0) red[u][wvi] = m;
  }
  __syncthreads();
  if (t < 5)
    mxs[t] = fmaxf(fmaxf(red[t][0], red[t][1]), fmaxf(red[t][2], red[t][3]));
  __syncthreads();

  // pass 2: exp own element + sum
  #pragma unroll
  for (int u = 0; u < 5; ++u) {
    float p = expf(sc[u][t] - mxs[u]);
    sc[u][t] = p;
    #pragma unroll
    for (int off = 32; off; off >>= 1) p += __shfl_down(p, off);
    if (lane == 0) red[u][wvi] = p;
  }
  __syncthreads();

  // pass 3: PV over 64 keys per wave-chunk
  int e = t & 63, cq = t >> 6;
  float acc[5] = {};
  for (int kk = cq * 64; kk < (cq + 1) * 64; ++kk) {
    float vv = v[((size_t)bh * LSEQ + k0 + kk) * DH + e];
    #pragma unroll
    for (int u = 0; u < 5; ++u) acc[u] += sc[u][kk] * vv;
  }
  #pragma unroll
  for (int u = 0; u < 5; ++u) part[cq][u][e] = acc[u];
  __syncthreads();

  const int slot = (bh * 7 + uc) * 4 + qtr;
  if (t < 5) {
    pm[slot * 5 + t] = mxs[t];
    ps[slot * 5 + t] = red[t][0] + red[t][1] + red[t][2] + red[t][3];
  }
  for (int i = t; i < 5 * DH; i += 256) {
    int u = i >> 6, ee = i & 63;
    po[((size_t)slot * 5 + u) * 64 + ee] =
        part[0][u][ee] + part[1][u][ee] + part[2][u][ee] + part[3][u][ee];
  }
}

// ---------------- merge 4 partials -> ctxh (selected rows) -------------------
__global__ void __launch_bounds__(256) attn_merge(const float* __restrict__ pm,
                                                  const float* __restrict__ ps,
                                                  const float* __restrict__ po,
                                                  const int* __restrict__ top,
                                                  u16* __restrict__ ctxh) {
  const int bid = blockIdx.x;                        // 448
  const int c6 = bid & 63, uc = bid >> 6;
  const int bh = ((c6 & 7) << 3) | (c6 >> 3);
  const int t = threadIdx.x;
  const int base = (bh * 7 + uc) * 4;
  __shared__ float wgt[5][4];
  __shared__ float inv[5];
  __shared__ int rows[5];
  if (t < 5) {
    rows[t] = top[bh * UTOP + uc * 5 + t];
    float m0 = pm[(base + 0) * 5 + t], m1 = pm[(base + 1) * 5 + t];
    float m2 = pm[(base + 2) * 5 + t], m3 = pm[(base + 3) * 5 + t];
    float M = fmaxf(fmaxf(m0, m1), fmaxf(m2, m3));
    float w0 = expf(m0 - M), w1 = expf(m1 - M);
    float w2 = expf(m2 - M), w3 = expf(m3 - M);
    float S = ps[(base + 0) * 5 + t] * w0 + ps[(base + 1) * 5 + t] * w1 +
              ps[(base + 2) * 5 + t] * w2 + ps[(base + 3) * 5 + t] * w3;
    wgt[t][0] = w0; wgt[t][1] = w1; wgt[t][2] = w2; wgt[t][3] = w3;
    inv[t] = 1.0f / S;
  }
  __syncthreads();
  for (int i = t; i < 5 * DH; i += 256) {
    int u = i >> 6, e = i & 63;
    float o = po[((size_t)(base + 0) * 5 + u) * 64 + e] * wgt[u][0] +
              po[((size_t)(base + 1) * 5 + u) * 64 + e] * wgt[u][1] +
              po[((size_t)(base + 2) * 5 + u) * 64 + e] * wgt[u][2] +
              po[((size_t)(base + 3) * 5 + u) * 64 + e] * wgt[u][3];
    float s = o * inv[u];
    size_t lin = ((size_t)bh * LSEQ + rows[u]) * DH + e;
    ctxh[(lin >> 9) * 512 + (lin & 511)] = f2h(s);
  }
}

// ---------------- layernorm over D=512 (in [+ in2]); fp32 out + fp16 xh ----
__global__ void __launch_bounds__(256) ln_k(const float* __restrict__ in,
                                            const float* __restrict__ in2,
                                            const float* __restrict__ g,
                                            const float* __restrict__ be,
                                            float* __restrict__ out,
                                            u16* __restrict__ oh,
                                            const float* __restrict__ mark) {
  int row = blockIdx.x, t = threadIdx.x;
  size_t o0 = (size_t)row * DMODEL + t, o1 = o0 + 256;
  float x0 = in[o0], x1 = in[o1];
  if (in2) { x0 += in2[o0]; x1 += in2[o1]; }
  __shared__ float red[256];
  red[t] = x0 + x1; __syncthreads();
  for (int s = 128; s; s >>= 1) { if (t < s) red[t] += red[t + s]; __syncthreads(); }
  float mean = red[0] * (1.0f / DMODEL);
  __syncthreads();
  float d0 = x0 - mean, d1 = x1 - mean;
  red[t] = d0 * d0 + d1 * d1; __syncthreads();
  for (int s = 128; s; s >>= 1) { if (t < s) red[t] += red[t + s]; __syncthreads(); }
  float rstd = 1.0f / sqrtf(red[0] * (1.0f / DMODEL) + 1e-5f);
  float v0 = d0 * rstd * g[t] + be[t];
  float v1 = d1 * rstd * g[t + 256] + be[t + 256];
  if (mark) { float mk = mark[row]; v0 *= mk; v1 *= mk; }
  if (out) { out[o0] = v0; out[o1] = v1; }
  if (oh) {
    oh[o0] = f2h(v0);
    oh[o1] = f2h(v1);
  }
}

// ---------------- final fc: split-K two-stage ----------------
__global__ void __launch_bounds__(256) fc_stage1(const float* __restrict__ y,
                                                 const float* __restrict__ fw,
                                                 float* __restrict__ part) {
  int blk = blockIdx.x;
  int k0 = blk * 1024;
  int tid = threadIdx.x;
  __shared__ float ys[NB][1024];
  #pragma unroll
  for (int b = 0; b < NB; ++b)
    *(float4*)&ys[b][tid * 4] = *(const float4*)&y[(size_t)b * (LSEQ * DMODEL) + k0 + tid * 4];
  __syncthreads();
  int c = tid & 15, ks = tid >> 4;
  float acc[NB] = {};
  const float* wp = fw + (size_t)c * (LSEQ * DMODEL) + k0 + ks * 64;
  for (int j = 0; j < 16; ++j) {
    int jj = (j + ks) & 15;
    float4 w4 = *(const float4*)&wp[jj * 4];
    #pragma unroll
    for (int b = 0; b < NB; ++b) {
      float4 yv = *(const float4*)&ys[b][ks * 64 + jj * 4];
      acc[b] += yv.x * w4.x + yv.y * w4.y + yv.z * w4.z + yv.w * w4.w;
    }
  }
  __shared__ float rs[16][128];
  #pragma unroll
  for (int b = 0; b < NB; ++b) rs[ks][b * 16 + c] = acc[b];
  __syncthreads();
  if (tid < 128) {
    float s = 0.f;
    #pragma unroll
    for (int i = 0; i < 16; ++i) s += rs[i][tid];
    part[(size_t)tid * 512 + blk] = s;
  }
}

__global__ void __launch_bounds__(128) fc_stage2(const float* __restrict__ part,
                                                 const float* __restrict__ fb,
                                                 float* __restrict__ out) {
  int bc = threadIdx.x;
  float s = 0.f;
  for (int i = 0; i < 512; ++i) s += part[(size_t)bc * 512 + i];
  out[bc] = s + fb[bc & 15];
}

// ---------------- host launch ----------------
extern "C" void kernel_launch(void* const* d_in, const int* in_sizes, int n_in,
                              void* d_out, int out_size, void* d_ws, size_t ws_size,
                              hipStream_t stream) {
  (void)in_sizes; (void)n_in; (void)out_size; (void)ws_size;
  const float* x_enc  = (const float*)d_in[0];
  const float* x_mark = (const float*)d_in[1];
  const float* conv_w = (const float*)d_in[2];
  const float* Wq = (const float*)d_in[3];
  const float* bq = (const float*)d_in[4];
  const float* Wk = (const float*)d_in[5];
  const float* bk = (const float*)d_in[6];
  const float* Wv = (const float*)d_in[7];
  const float* bv = (const float*)d_in[8];
  const float* Wo = (const float*)d_in[9];
  const float* bo = (const float*)d_in[10];
  const float* W1 = (const float*)d_in[11];
  const float* b1 = (const float*)d_in[12];
  const float* W2 = (const float*)d_in[13];
  const float* b2 = (const float*)d_in[14];
  const float* g1 = (const float*)d_in[15];
  const float* be1= (const float*)d_in[16];
  const float* g2 = (const float*)d_in[17];
  const float* be2= (const float*)d_in[18];
  const float* gF = (const float*)d_in[19];
  const float* bF = (const float*)d_in[20];
  const float* fcw= (const float*)d_in[21];
  const float* fcb= (const float*)d_in[22];
  float* out = (float*)d_out;

  const size_t NBLD = (size_t)NB * LSEQ * DMODEL;       // 4,194,304
  float* ws   = (float*)d_ws;
  float* xb   = ws;                    // residual fp32
  float* pre0 = xb   + NBLD;           // pre-LN fp32
  float* qb   = pre0 + NBLD;           // q fp32; later preB; later hidh (with kb)
  float* kb   = qb   + NBLD;
  float* vb   = kb   + NBLD;           // v fp32; later preC
  u16*  xh    = (u16*)(vb + NBLD);     // NBLD u16
  u16*  ctxh  = xh + NBLD;             // NBLD u16
  u16*  Wcat  = ctxh + NBLD;           // fp16 weights, all layers (9,437,184 u16)
  float* Mb   = (float*)(Wcat + (size_t)NLAYER * WPERL);
  float* vm   = Mb + (size_t)NB * NH * LSEQ;
  float* part = vm + NB * NH * DH;
  int* idxb   = (int*)(part + 512 * 128);
  int* topb   = idxb + LSEQ * UTOP;
  float* pmb  = (float*)(topb + NB * NH * UTOP);   // 1792*5
  float* psb  = pmb + 1792 * 5;                    // 1792*5
  float* pob  = psb + 1792 * 5;                    // 1792*5*64
  u16* hidh   = (u16*)qb;              // 8192 x 2048 u16 == [qb|kb] exactly
  float* preB = qb;                    // Wo slice-1 partial (q dead by then)
  float* preC = vb;                    // W2 slice-1 partial (v dead by then)

  // all weights -> fp16, one dispatch
  cvt_all<<<2048, 256, 0, stream>>>(Wq, Wk, Wv, Wo, W1, W2, Wcat);

  {
    dim3 gc(8, 32, NB);
    conv_pe<<<gc, 256, 0, stream>>>(x_enc, conv_w, xb, xh);
  }

  dim3 gqkv(6,  32);       // 256x256 tiles: N=1536, K=512 (nt=8), 192 blocks
  dim3 gw1 (8,  32);       // 256x256 tiles: N=2048, K=512 (nt=8), 256 blocks
  dim3 gwo (4,  64, 2);    // 128 tiles, K=512 split-K 2 (kslice 256, nt=4)
  dim3 gw2 (4,  64, 2);    // 128 tiles, K=2048 split-K 2 (kslice 1024, nt=16)

  for (int l = 0; l < NLAYER; ++l) {
    const u16* Wl    = Wcat + (size_t)l * WPERL;
    const u16* Wc_qkv= Wl;                   // 1536 x 512
    const u16* Wc_o  = Wl + 786432;          //  512 x 512
    const u16* Wc_1  = Wl + 1048576;         // 2048 x 512
    const u16* Wc_2  = Wl + 2097152;         //  512 x 2048

    // fused QKV (mode 3) -> qb/kb/vb
    gemm256<<<gqkv, 512, 0, stream>>>(xh, Wc_qkv,
                                      bq + l*DMODEL, bk + l*DMODEL, bv + l*DMODEL,
                                      qb, nullptr, 512, 1536, 3);

    // prob-attention
    uint32_t lk0, lk1, k2_0, k2_1;
    tf2x32(0u, 42u, 0u, (uint32_t)l, lk0, lk1);
    tf2x32(lk0, lk1, 0u, 1u, k2_0, k2_1);
    gen_idx_kernel<<<140, 256, 0, stream>>>(k2_0, k2_1, idxb);
    sampled_m<<<NB * NH * LSEQ / 4, 256, 0, stream>>>(qb, kb, idxb, Mb);
    topk35<<<NB * NH, 256, 0, stream>>>(Mb, topb);
    vmean_k<<<NB * NH, 256, 0, stream>>>(vb, vm);
    ctx_fillb<<<(NB * NH * LSEQ * DH) / 1024, 256, 0, stream>>>(vm, ctxh);
    attn_part<<<1792, 256, 0, stream>>>(qb, kb, vb, topb, pmb, psb, pob);
    attn_merge<<<448, 256, 0, stream>>>(pmb, psb, pob, topb, ctxh);

    // Wo (+resid xb), split-K 2 -> pre0 / preB ; LN1 -> xb + xh
    gemm_cat<<<gwo, 256, 0, stream>>>(ctxh, Wc_o, bo + l*DMODEL,
                                      xb, pre0, preB, 512, 256, 512);
    ln_k<<<NB * LSEQ, 256, 0, stream>>>(pre0, preB, g1 + l*DMODEL, be1 + l*DMODEL,
                                        xb, xh, nullptr);

    // FFN: W1 relu -> hidh fp16; W2 split-K 2 -> pre0/preC; LN2
    gemm256<<<gw1, 512, 0, stream>>>(xh, Wc_1,
                                     b1 + l*DFF, nullptr, nullptr,
                                     nullptr, hidh, 512, 2048, 1);
    gemm_cat<<<gw2, 256, 0, stream>>>(hidh, Wc_2, b2 + l*DMODEL,
                                      xb, pre0, preC, 2048, 1024, 512);
    ln_k<<<NB * LSEQ, 256, 0, stream>>>(pre0, preC, g2 + l*DMODEL, be2 + l*DMODEL,
                                        xb, xh, nullptr);
  }

  // final LN (*mark) -> pre0 ; split-K fc
  ln_k<<<NB * LSEQ, 256, 0, stream>>>(xb, nullptr, gF, bF, pre0, nullptr, x_mark);
  fc_stage1<<<512, 256, 0, stream>>>(pre0, fcw, part);
  fc_stage2<<<1, 128, 0, stream>>>(part, fcb, out);
}